// Round 4
// baseline (183.904 us; speedup 1.0000x reference)
//
#include <hip/hip_runtime.h>

#define IRREPS 240
#define NPB 4   // nodes per block = waves per block

// ---------- CSR build ----------
__global__ void histogram_kernel(const int* __restrict__ eidx, int* __restrict__ counts,
                                 int n_edges) {
    int e = blockIdx.x * blockDim.x + threadIdx.x;
    if (e >= n_edges) return;
    int2 p = reinterpret_cast<const int2*>(eidx)[e];
    atomicAdd(&counts[p.y], 1);
}

__global__ void scan_kernel(const int* __restrict__ counts, int* __restrict__ offsets,
                            int* __restrict__ cursor, int n) {
    __shared__ int part[1024];
    int t = threadIdx.x;
    int per = (n + 1023) / 1024;
    int start = t * per;
    int end = min(start + per, n);
    int sum = 0;
    for (int i = start; i < end; ++i) sum += counts[i];
    part[t] = sum;
    __syncthreads();
    for (int off = 1; off < 1024; off <<= 1) {
        int v = (t >= off) ? part[t - off] : 0;
        __syncthreads();
        part[t] += v;
        __syncthreads();
    }
    int run = (t == 0) ? 0 : part[t - 1];
    for (int i = start; i < end; ++i) {
        offsets[i] = run;
        cursor[i] = run;
        run += counts[i];
    }
}

__global__ void fill_kernel(const int* __restrict__ eidx, int* __restrict__ cursor,
                            int* __restrict__ edge_ids, int n_edges) {
    int e = blockIdx.x * blockDim.x + threadIdx.x;
    if (e >= n_edges) return;
    int2 p = reinterpret_cast<const int2*>(eidx)[e];
    int pos = atomicAdd(&cursor[p.y], 1);
    edge_ids[pos] = e;
}

// ---------- fused gather + equivariant linear ----------
// Block = 256 threads = 4 waves; wave w owns node blockIdx*4+w.
// Gather phase is wave-private: no __syncthreads, edge ids broadcast via __shfl,
// ~cnt independent float4 row loads in flight per wave (unroll 8).
__global__ void gather_linear_kernel(const float* __restrict__ msgs,
                                     const float* __restrict__ cutoff,
                                     const int* __restrict__ edge_ids,
                                     const int* __restrict__ offsets,
                                     const int* __restrict__ counts,
                                     const float* __restrict__ W0,
                                     const float* __restrict__ W1,
                                     const float* __restrict__ W2,
                                     float* __restrict__ out,
                                     int n_nodes) {
    __shared__ float s_node[NPB][IRREPS];

    int t = threadIdx.x;
    int w = t >> 6;
    int lane = t & 63;
    int n = blockIdx.x * NPB + w;

    float4 acc = make_float4(0.f, 0.f, 0.f, 0.f);

    if (n < n_nodes) {
        int beg = offsets[n];
        int cnt = counts[n];
        for (int base = 0; base < cnt; base += 64) {
            int bn = min(64, cnt - base);   // wave-uniform
            int myeid = 0;
            float myw = 0.f;
            if (lane < bn) {
                myeid = edge_ids[beg + base + lane];
                myw = cutoff[myeid];
            }
            #pragma unroll 8
            for (int j = 0; j < bn; ++j) {
                int e = __shfl(myeid, j);
                float wgt = __shfl(myw, j);
                if (lane < 60) {
                    const float4 m = *reinterpret_cast<const float4*>(
                        msgs + (long long)e * IRREPS + lane * 4);
                    acc.x += m.x * wgt;
                    acc.y += m.y * wgt;
                    acc.z += m.z * wgt;
                    acc.w += m.w * wgt;
                }
            }
        }
    }

    if (lane < 60) {
        *reinterpret_cast<float4*>(&s_node[w][lane * 4]) = acc;
    }
    __syncthreads();

    // linear phase: 4 rounds, whole block per node
    for (int j = 0; j < NPB; ++j) {
        int nd = blockIdx.x * NPB + j;
        if (nd >= n_nodes) break;
        if (t < IRREPS) {
            const float* s = s_node[j];
            float a = 0.f;
            float res;
            if (t < 64) {
                int o = t;
                #pragma unroll 8
                for (int i = 0; i < 64; ++i) a += W0[o * 64 + i] * s[i];
                res = a * 0.125f;               // 1/sqrt(64)
            } else if (t < 160) {
                int rel = t - 64;
                int o = rel / 3, d = rel % 3;
                #pragma unroll 8
                for (int i = 0; i < 32; ++i) a += W1[o * 32 + i] * s[64 + i * 3 + d];
                res = a * 0.17677669529663687f; // 1/sqrt(32)
            } else {
                int rel = t - 160;
                int o = rel / 5, d = rel % 5;
                #pragma unroll
                for (int i = 0; i < 16; ++i) a += W2[o * 16 + i] * s[160 + i * 5 + d];
                res = a * 0.25f;                // 1/sqrt(16)
            }
            out[(long long)nd * IRREPS + t] = res;
        }
    }
}

extern "C" void kernel_launch(void* const* d_in, const int* in_sizes, int n_in,
                              void* d_out, int out_size, void* d_ws, size_t ws_size,
                              hipStream_t stream) {
    const float* msgs   = (const float*)d_in[0];
    const int*   eidx   = (const int*)d_in[1];
    const float* cutoff = (const float*)d_in[2];
    const float* W0     = (const float*)d_in[3];
    const float* W1     = (const float*)d_in[4];
    const float* W2     = (const float*)d_in[5];

    int n_edges = in_sizes[0] / IRREPS;
    int n_nodes = out_size / IRREPS;

    int* counts   = (int*)d_ws;
    int* offsets  = counts + n_nodes;
    int* cursor   = offsets + n_nodes;
    int* edge_ids = cursor + n_nodes;

    hipMemsetAsync(counts, 0, (size_t)n_nodes * sizeof(int), stream);

    int block = 256;
    int egrid = (n_edges + block - 1) / block;
    histogram_kernel<<<egrid, block, 0, stream>>>(eidx, counts, n_edges);
    scan_kernel<<<1, 1024, 0, stream>>>(counts, offsets, cursor, n_nodes);
    fill_kernel<<<egrid, block, 0, stream>>>(eidx, cursor, edge_ids, n_edges);

    int ngrid = (n_nodes + NPB - 1) / NPB;
    gather_linear_kernel<<<ngrid, 256, 0, stream>>>(
        msgs, cutoff, edge_ids, offsets, counts, W0, W1, W2, (float*)d_out, n_nodes);
}